// Round 5
// baseline (754.170 us; speedup 1.0000x reference)
//
#include <hip/hip_runtime.h>
#include <hip/hip_fp16.h>

// VQ codebook argmin: N=32768 x K=8192 x D=256 fp32.
// f16 hi/lo split (3 MFMA terms) = fp32-accurate dots on the matrix pipe.
//
// R2: 370us MfmaUtil 51%, 0 conflicts. Model: 64x64 wave tile needs 84.6
//     B/cyc/CU LDS-read = 100% of b128 ceiling -> LDS-read bound.
// R4: FAILED: same-wave DMA+ds_read overlap -> 4 cyc conflict per read.
// R5: wave tile 64x128 (2x4 of 32x32x16) -> 0.0156 B/FLOP = 74% LDS;
//     block 64q x 512c (4 waves share rows), strict 2-barrier phasing
//     (R4 lesson), running argmin via per-ct shfl+LDS (register relief).

#define N_Q   32768
// ws offsets in halves
#define ZH_OFF 0u
#define ZL_OFF 8388608u    // 16MB
#define EH_OFF 16777216u   // 32MB
#define EL_OFF 18874368u   // 36MB

typedef _Float16 half8 __attribute__((ext_vector_type(8)));
typedef _Float16 half4 __attribute__((ext_vector_type(4)));
typedef float    f32x16 __attribute__((ext_vector_type(16)));

__device__ __forceinline__ void gl_lds16(const _Float16* g, _Float16* l) {
  __builtin_amdgcn_global_load_lds(
      (const __attribute__((address_space(1))) unsigned int*)g,
      (__attribute__((address_space(3))) unsigned int*)l, 16, 0, 0);
}

// ---------------- prep: z -> (hi,lo) f16, scale 2^4 ----------------
__global__ void vq_prep_z(const float* __restrict__ z,
                          _Float16* __restrict__ zh, _Float16* __restrict__ zl) {
  int i = blockIdx.x * 256 + threadIdx.x;
  float4 v = ((const float4*)z)[i];
  float xs[4] = {v.x * 16.0f, v.y * 16.0f, v.z * 16.0f, v.w * 16.0f};
  half4 h, l;
#pragma unroll
  for (int j = 0; j < 4; ++j) {
    _Float16 hj = (_Float16)xs[j];
    h[j] = hj;
    l[j] = (_Float16)(xs[j] - (float)hj);
  }
  ((half4*)zh)[i] = h;
  ((half4*)zl)[i] = l;
}

// ------- prep: codebook -> (hi,lo) f16 scale 2^15, plus 2^19*||e||^2 -------
__global__ void vq_prep_cb(const float* __restrict__ cb,
                           _Float16* __restrict__ eh, _Float16* __restrict__ el,
                           float* __restrict__ cbs) {
  int w = threadIdx.x >> 6, lane = threadIdx.x & 63;
  int code = blockIdx.x * 4 + w;
  float4 v = ((const float4*)cb)[code * 64 + lane];
  float ss = v.x * v.x + v.y * v.y + v.z * v.z + v.w * v.w;
  float xs[4] = {v.x * 32768.0f, v.y * 32768.0f, v.z * 32768.0f, v.w * 32768.0f};
  half4 h, l;
#pragma unroll
  for (int j = 0; j < 4; ++j) {
    _Float16 hj = (_Float16)xs[j];
    h[j] = hj;
    l[j] = (_Float16)(xs[j] - (float)hj);
  }
  ((half4*)eh)[code * 64 + lane] = h;
  ((half4*)el)[code * 64 + lane] = l;
#pragma unroll
  for (int off = 1; off < 64; off <<= 1) ss += __shfl_xor(ss, off);
  if (lane == 0) cbs[code] = ss * 524288.0f;   // 2^19 = 2^4 * 2^15
}

// ---------------- main: fused GEMM + argmin ----------------
// Block: 256 thr = 4 waves, ALL sharing query rows q0..q0+63; wave w owns
// cols w*128..w*128+127 of the 512-code tile. Wave tile 64x128 = 2x4 grid
// of 32x32x16 MFMA. Grid: 512 q-blocks x 4 code-splits = 2048 (2/CU, 4 gen).
// LDS chunk per kk (K32): A 64x32x2hl = 8KB | B 512x32x2hl = 64KB.
// Row line = 32 halves = 4 x 16B blocks; block g at p = g ^ (row&3).
__global__ __launch_bounds__(256, 2)
void vq_main(const _Float16* __restrict__ ws,
             const float* __restrict__ cbs,
             unsigned long long* __restrict__ partials) {
  __shared__ __align__(16) _Float16 S[36864];   // Ah|Al|Bh|Bl = 72KB
  __shared__ unsigned long long red[4][64];

  const int tid = threadIdx.x;
  const int lane = tid & 63;
  const int w   = tid >> 6;
  const int l31 = lane & 31;
  const int l5  = lane >> 5;

  const int qb    = blockIdx.x >> 2;
  const int split = blockIdx.x & 3;
  const int q0    = qb * 64;
  const int c0    = split * 2048;

  // ---- staging addresses ----
  // A: 256 blocks of 16B per hl; thread -> block tid.
  const int rA = tid >> 2;
  const int gA = (tid & 3) ^ (rA & 3);
  const unsigned srcA = (unsigned)(q0 + rA) * 256u + (unsigned)(gA << 3);
  // B: 2048 blocks per hl; thread -> blocks c*256+tid, c=0..7.
  unsigned rBg[8];
#pragma unroll
  for (int c = 0; c < 8; ++c) {
    int bi = c * 256 + tid;
    int r  = bi >> 2;
    int g  = (bi & 3) ^ (r & 3);
    rBg[c] = (unsigned)r * 256u + (unsigned)(g << 3);
  }

  // ---- fragment LDS offsets (halves) ----
  // A row ra: line at ra*32; block g = k2*2+l5 at p = g^(ra&3).
  int offA[2][2][2], offB[4][2][2];   // [mt/nt][k2][hl]
#pragma unroll
  for (int mt = 0; mt < 2; ++mt) {
    int ra = mt * 32 + l31;
#pragma unroll
    for (int k2 = 0; k2 < 2; ++k2) {
      int g = k2 * 2 + l5;
      int p = (g ^ (ra & 3)) << 3;
#pragma unroll
      for (int hl = 0; hl < 2; ++hl)
        offA[mt][k2][hl] = hl * 2048 + ra * 32 + p;
    }
  }
#pragma unroll
  for (int nt = 0; nt < 4; ++nt) {
    int rb = w * 128 + nt * 32 + l31;
#pragma unroll
    for (int k2 = 0; k2 < 2; ++k2) {
      int g = k2 * 2 + l5;
      int p = (g ^ (rb & 3)) << 3;
#pragma unroll
      for (int hl = 0; hl < 2; ++hl)
        offB[nt][k2][hl] = 4096 + hl * 16384 + rb * 32 + p;
    }
  }

  unsigned long long run = ~0ull;   // rows owned by tid<64 at the end

  for (int ct = 0; ct < 4; ++ct) {
    const int crow0 = c0 + ct * 512;
    const unsigned bbase = (unsigned)crow0 * 256u;

    f32x16 acc[2][4];
#pragma unroll
    for (int mt = 0; mt < 2; ++mt)
#pragma unroll
      for (int nt = 0; nt < 4; ++nt)
#pragma unroll
        for (int r = 0; r < 16; ++r) acc[mt][nt][r] = 0.0f;

    const int colbase = crow0 + w * 128 + l31;
    float cbsv[4];
#pragma unroll
    for (int nt = 0; nt < 4; ++nt) cbsv[nt] = cbs[colbase + nt * 32];

    for (int kk = 0; kk < 8; ++kk) {
      const unsigned kcol = (unsigned)(kk << 5);
      __syncthreads();   // WAR: prior reads of S done everywhere
      // ---- stage (strict phase: no ds_read while DMA in flight - R4 lesson)
      gl_lds16(ws + ZH_OFF + srcA + kcol, &S[w * 512]);
      gl_lds16(ws + ZL_OFF + srcA + kcol, &S[2048 + w * 512]);
#pragma unroll
      for (int c = 0; c < 8; ++c) {
        gl_lds16(ws + EH_OFF + bbase + kcol + rBg[c], &S[4096  + c * 2048 + w * 512]);
        gl_lds16(ws + EL_OFF + bbase + kcol + rBg[c], &S[20480 + c * 2048 + w * 512]);
      }
      __syncthreads();   // drains vmcnt(0): staged data visible

      // ---- compute: 2 x K16, 24 MFMAs each
#pragma unroll
      for (int k2 = 0; k2 < 2; ++k2) {
        half8 ah[2], al[2], bh[4], bl[4];
#pragma unroll
        for (int mt = 0; mt < 2; ++mt) {
          ah[mt] = *(const half8*)&S[offA[mt][k2][0]];
          al[mt] = *(const half8*)&S[offA[mt][k2][1]];
        }
#pragma unroll
        for (int nt = 0; nt < 4; ++nt) {
          bh[nt] = *(const half8*)&S[offB[nt][k2][0]];
          bl[nt] = *(const half8*)&S[offB[nt][k2][1]];
        }
#pragma unroll
        for (int mt = 0; mt < 2; ++mt)
#pragma unroll
          for (int nt = 0; nt < 4; ++nt) {
            acc[mt][nt] = __builtin_amdgcn_mfma_f32_32x32x16_f16(
                ah[mt], bh[nt], acc[mt][nt], 0, 0, 0);
            acc[mt][nt] = __builtin_amdgcn_mfma_f32_32x32x16_f16(
                ah[mt], bl[nt], acc[mt][nt], 0, 0, 0);
            acc[mt][nt] = __builtin_amdgcn_mfma_f32_32x32x16_f16(
                al[mt], bh[nt], acc[mt][nt], 0, 0, 0);
          }
      }
    }

    // ---- per-ct epilogue: dist = 2^19*cb_sq - 2*acc, argmin over this
    // wave's 128 cols, fold into per-row LDS table (register relief).
#pragma unroll
    for (int mt = 0; mt < 2; ++mt)
#pragma unroll
      for (int r = 0; r < 16; ++r) {
        float d = fmaf(-2.0f, acc[mt][0][r], cbsv[0]);
        unsigned ci = (unsigned)colbase;
#pragma unroll
        for (int nt = 1; nt < 4; ++nt) {
          float dn = fmaf(-2.0f, acc[mt][nt][r], cbsv[nt]);
          if (dn < d) { d = dn; ci = (unsigned)(colbase + nt * 32); }
        }
        // reduce over the 32 lanes of this half-wave (32 distinct cols)
#pragma unroll
        for (int off = 1; off < 32; off <<= 1) {
          float od = __shfl_xor(d, off);
          unsigned oc = __shfl_xor(ci, off);
          if (od < d || (od == d && oc < ci)) { d = od; ci = oc; }
        }
        if (l31 == 0) {
          int row = mt * 32 + (r & 3) + 8 * (r >> 2) + 4 * l5;
          unsigned u = __float_as_uint(d);
          u = (u & 0x80000000u) ? ~u : (u | 0x80000000u);  // orderable
          red[w][row] = ((unsigned long long)u << 32) | ci;
        }
      }
    __syncthreads();
    if (tid < 64) {
      unsigned long long v0 = red[0][tid], v1 = red[1][tid];
      unsigned long long v2 = red[2][tid], v3 = red[3][tid];
      if (v1 < v0) v0 = v1;
      if (v3 < v2) v2 = v3;
      if (v2 < v0) v0 = v2;
      if (v0 < run) run = v0;   // ties -> lower code (code in low bits)
    }
  }

  if (tid < 64)
    partials[(size_t)split * N_Q + q0 + tid] = run;
}

// ---------------- final: combine 4 splits, write INT32 indices ----------------
__global__ void vq_final(const unsigned long long* __restrict__ partials,
                         int* __restrict__ out) {
  int i = blockIdx.x * 256 + threadIdx.x;
  unsigned long long m = partials[i];
#pragma unroll
  for (int s = 1; s < 4; ++s) {
    unsigned long long v = partials[(size_t)s * N_Q + i];
    if (v < m) m = v;
  }
  out[i] = (int)(unsigned)(m & 0xffffffffull);
}

extern "C" void kernel_launch(void* const* d_in, const int* in_sizes, int n_in,
                              void* d_out, int out_size, void* d_ws, size_t ws_size,
                              hipStream_t stream) {
  const float* z  = (const float*)d_in[0];   // [32,32,32,256] fp32
  const float* cb = (const float*)d_in[1];   // [8192,256] fp32
  char* ws = (char*)d_ws;
  // ws: zh 16M | zl 16M | eh 4M | el 4M | cbs 32K | partials 1M
  _Float16* zh = (_Float16*)(ws);
  _Float16* zl = (_Float16*)(ws + (size_t)16 * 1024 * 1024);
  _Float16* eh = (_Float16*)(ws + (size_t)32 * 1024 * 1024);
  _Float16* el = (_Float16*)(ws + (size_t)36 * 1024 * 1024);
  float*    cbs = (float*)(ws + (size_t)40 * 1024 * 1024);
  unsigned long long* partials =
      (unsigned long long*)(ws + (size_t)40 * 1024 * 1024 + 65536);

  hipLaunchKernelGGL(vq_prep_z,  dim3(8192), dim3(256), 0, stream, z, zh, zl);
  hipLaunchKernelGGL(vq_prep_cb, dim3(2048), dim3(256), 0, stream, cb, eh, el, cbs);
  hipLaunchKernelGGL(vq_main,    dim3(2048), dim3(256), 0, stream,
                     (const _Float16*)ws, cbs, partials);
  hipLaunchKernelGGL(vq_final,   dim3(128),  dim3(256), 0, stream,
                     partials, (int*)d_out);
}

// Round 6
// 597.949 us; speedup vs baseline: 1.2613x; 1.2613x over previous
//
#include <hip/hip_runtime.h>
#include <hip/hip_fp16.h>

// VQ codebook argmin: N=32768 x K=8192 x D=256 fp32.
// f16 hi/lo split (3 MFMA terms) = fp32-accurate dots (absmax 0, proven R2-R5).
//
// R2: 370us, 51% Mfma - exactly at LDS ds_read_b128 ceiling (21 B/cyc/SIMD).
// R4/R5: conflict regressions; bank rule: each consecutive 8-lane group of a
//        b128 must cover all 8 bank-quads.
// R6: LDS is the wrong tool (B-frag reuse=1; LDS BW 85 B/cyc < L2 135 B/cyc).
//     Prep writes A/B in MFMA-fragment order; main kernel = coalesced
//     global_load_dwordx4 -> MFMA, zero LDS/barriers in K-loop. Block
//     64q x 512c, ct=16 covers all codes -> direct output, no split.

#define N_Q   32768
#define BF_OFF 16777216u   // halves: aF 32MB | bF 8MB | cbs

typedef _Float16 half8 __attribute__((ext_vector_type(8)));
typedef float    f32x16 __attribute__((ext_vector_type(16)));

// ---- prep: z -> fragment-ordered (hi,lo) f16, scale 2^4 ----
// aF chunk (qb32, kc, hl): 1KB = lane l's 16B at ((qb32*16+kc)*2+hl)*512 + l*8,
// lane = l5*32 + l31 holds rows qb32*32+l31, K-cols (kc*2+l5... wait kc is
// 16-col chunk: k = kc*16 + l5*8 + j.
__global__ void vq_prep_z(const float* __restrict__ z, _Float16* __restrict__ wsh) {
  int i = blockIdx.x * 256 + threadIdx.x;   // 1,048,576 = 32768 rows x 32 segs
  int row = i >> 5;
  int kseg = i & 31;                         // 8-col segment
  float4 v0 = ((const float4*)z)[i * 2];
  float4 v1 = ((const float4*)z)[i * 2 + 1];
  float xs[8] = {v0.x, v0.y, v0.z, v0.w, v1.x, v1.y, v1.z, v1.w};
  half8 h, l;
#pragma unroll
  for (int j = 0; j < 8; ++j) {
    float s = xs[j] * 16.0f;
    _Float16 hj = (_Float16)s;
    h[j] = hj;
    l[j] = (_Float16)(s - (float)hj);
  }
  unsigned qb32 = (unsigned)(row >> 5), l31 = (unsigned)(row & 31);
  unsigned kc = (unsigned)(kseg >> 1), l5 = (unsigned)(kseg & 1);
  unsigned lane = l5 * 32 + l31;
  unsigned base = (qb32 * 16u + kc) * 1024u + lane * 8u;   // hl=0
  *(half8*)&wsh[base] = h;
  *(half8*)&wsh[base + 512] = l;                            // hl=1
}

// ---- prep: codebook -> fragment-ordered (hi,lo) f16, scale 2^15 ----
__global__ void vq_prep_cb(const float* __restrict__ cb, _Float16* __restrict__ wsh) {
  int i = blockIdx.x * 256 + threadIdx.x;   // 262,144 = 8192 codes x 32 segs
  int row = i >> 5;
  int kseg = i & 31;
  float4 v0 = ((const float4*)cb)[i * 2];
  float4 v1 = ((const float4*)cb)[i * 2 + 1];
  float xs[8] = {v0.x, v0.y, v0.z, v0.w, v1.x, v1.y, v1.z, v1.w};
  half8 h, l;
#pragma unroll
  for (int j = 0; j < 8; ++j) {
    float s = xs[j] * 32768.0f;
    _Float16 hj = (_Float16)s;
    h[j] = hj;
    l[j] = (_Float16)(s - (float)hj);
  }
  unsigned cb32 = (unsigned)(row >> 5), l31 = (unsigned)(row & 31);
  unsigned kc = (unsigned)(kseg >> 1), l5 = (unsigned)(kseg & 1);
  unsigned lane = l5 * 32 + l31;
  unsigned base = BF_OFF + (cb32 * 16u + kc) * 1024u + lane * 8u;
  *(half8*)&wsh[base] = h;
  *(half8*)&wsh[base + 512] = l;
}

// ---- prep: 2^19 * ||e||^2 per code (unscaled squares, matching ref) ----
__global__ void vq_cbs(const float* __restrict__ cb, float* __restrict__ cbs) {
  int w = threadIdx.x >> 6, lane = threadIdx.x & 63;
  int code = blockIdx.x * 4 + w;
  float4 v = ((const float4*)cb)[code * 64 + lane];
  float ss = v.x * v.x + v.y * v.y + v.z * v.z + v.w * v.w;
#pragma unroll
  for (int off = 1; off < 64; off <<= 1) ss += __shfl_xor(ss, off);
  if (lane == 0) cbs[code] = ss * 524288.0f;   // 2^19 = 2^4 * 2^15
}

// ---- main: streaming fragment GEMM + fused argmin ----
// Block 256 thr = 4 waves sharing rows q0..q0+63; wave w owns cols
// w*128..+127 of each 512-code ct-tile. Wave tile 64x128 = 2x4 of
// 32x32x16 MFMA, 3 hi/lo terms. Grid 512 blocks = 2/CU. No LDS in K-loop.
__global__ __launch_bounds__(256, 2)
void vq_main(const _Float16* __restrict__ ws, const float* __restrict__ cbs,
             int* __restrict__ out) {
  __shared__ unsigned long long red[4][64];

  const int tid = threadIdx.x;
  const int lane = tid & 63;
  const int w = tid >> 6;
  const int l31 = lane & 31;
  const int l5 = lane >> 5;
  const unsigned qb32 = (unsigned)blockIdx.x * 2u;   // + mt
  const unsigned laneoff = (unsigned)lane * 8u;

  unsigned long long run = ~0ull;

  for (int ct = 0; ct < 16; ++ct) {
    f32x16 acc[2][4];
#pragma unroll
    for (int mt = 0; mt < 2; ++mt)
#pragma unroll
      for (int nt = 0; nt < 4; ++nt)
#pragma unroll
        for (int r = 0; r < 16; ++r) acc[mt][nt][r] = 0.0f;

    const unsigned cb32b = (unsigned)(ct * 16 + w * 4);   // + nt

#pragma unroll 2
    for (int kc = 0; kc < 16; ++kc) {
      half8 ah[2], al[2];
#pragma unroll
      for (int mt = 0; mt < 2; ++mt) {
        const _Float16* p = ws + ((qb32 + mt) * 16u + kc) * 1024u + laneoff;
        ah[mt] = *(const half8*)p;
        al[mt] = *(const half8*)(p + 512);
      }
#pragma unroll
      for (int nt = 0; nt < 4; ++nt) {
        const _Float16* p =
            ws + BF_OFF + ((cb32b + nt) * 16u + kc) * 1024u + laneoff;
        half8 bh = *(const half8*)p;
        half8 bl = *(const half8*)(p + 512);
#pragma unroll
        for (int mt = 0; mt < 2; ++mt) {
          acc[mt][nt] = __builtin_amdgcn_mfma_f32_32x32x16_f16(
              ah[mt], bh, acc[mt][nt], 0, 0, 0);
          acc[mt][nt] = __builtin_amdgcn_mfma_f32_32x32x16_f16(
              ah[mt], bl, acc[mt][nt], 0, 0, 0);
          acc[mt][nt] = __builtin_amdgcn_mfma_f32_32x32x16_f16(
              al[mt], bh, acc[mt][nt], 0, 0, 0);
        }
      }
    }

    // ---- epilogue: dist = 2^19*cb_sq - 2*acc; argmin over wave's 128 cols
    const int colbase = ct * 512 + w * 128 + l31;
    float cbsv[4];
#pragma unroll
    for (int nt = 0; nt < 4; ++nt) cbsv[nt] = cbs[colbase + nt * 32];
#pragma unroll
    for (int mt = 0; mt < 2; ++mt)
#pragma unroll
      for (int r = 0; r < 16; ++r) {
        float d = fmaf(-2.0f, acc[mt][0][r], cbsv[0]);
        unsigned ci = (unsigned)colbase;
#pragma unroll
        for (int nt = 1; nt < 4; ++nt) {
          float dn = fmaf(-2.0f, acc[mt][nt][r], cbsv[nt]);
          if (dn < d) { d = dn; ci = (unsigned)(colbase + nt * 32); }
        }
#pragma unroll
        for (int off = 1; off < 32; off <<= 1) {
          float od = __shfl_xor(d, off);
          unsigned oc = __shfl_xor(ci, off);
          if (od < d || (od == d && oc < ci)) { d = od; ci = oc; }
        }
        if (l31 == 0) {
          int row = mt * 32 + (r & 3) + 8 * (r >> 2) + 4 * l5;  // C layout
          unsigned u = __float_as_uint(d);
          u = (u & 0x80000000u) ? ~u : (u | 0x80000000u);       // orderable
          red[w][row] = ((unsigned long long)u << 32) | ci;
        }
      }
    __syncthreads();
    if (tid < 64) {
      unsigned long long v0 = red[0][tid], v1 = red[1][tid];
      unsigned long long v2 = red[2][tid], v3 = red[3][tid];
      if (v1 < v0) v0 = v1;
      if (v3 < v2) v2 = v3;
      if (v2 < v0) v0 = v2;
      if (v0 < run) run = v0;   // ties -> lower code (code in low bits)
    }
    __syncthreads();
  }

  if (tid < 64)
    out[blockIdx.x * 64 + tid] = (int)(unsigned)(run & 0xffffffffull);
}

extern "C" void kernel_launch(void* const* d_in, const int* in_sizes, int n_in,
                              void* d_out, int out_size, void* d_ws, size_t ws_size,
                              hipStream_t stream) {
  const float* z  = (const float*)d_in[0];   // [32,32,32,256] fp32
  const float* cb = (const float*)d_in[1];   // [8192,256] fp32
  _Float16* wsh = (_Float16*)d_ws;           // aF 32MB | bF 8MB | cbs 32KB
  float* cbs = (float*)((char*)d_ws + (size_t)40 * 1024 * 1024);

  hipLaunchKernelGGL(vq_prep_z,  dim3(4096), dim3(256), 0, stream, z, wsh);
  hipLaunchKernelGGL(vq_prep_cb, dim3(1024), dim3(256), 0, stream, cb, wsh);
  hipLaunchKernelGGL(vq_cbs,     dim3(2048), dim3(256), 0, stream, cb, cbs);
  hipLaunchKernelGGL(vq_main,    dim3(512),  dim3(256), 0, stream,
                     (const _Float16*)wsh, cbs, (int*)d_out);
}